// Round 7
// baseline (66328.632 us; speedup 1.0000x reference)
//
#include <hip/hip_runtime.h>
#include <stdint.h>

typedef __bf16 bf16;
typedef __bf16 bf16x8 __attribute__((ext_vector_type(8)));
typedef float f32x4 __attribute__((ext_vector_type(4)));

// ---------------------------------------------------------------------------
// Weight pre-pack: f32 [N,K] row-major -> split hi/lo bf16 in MFMA B-frag
// streaming layout: pk[half][nf][ks][lane][8],  lane = (n&15) | (((k&31)>>3)<<4),
// ks = k>>5, e = k&7.  One 16B load per (lane, nf, ks, half), fully coalesced.
// ---------------------------------------------------------------------------
__global__ void pack_split(const float* __restrict__ src, bf16* __restrict__ dst,
                           int N, int K, int NFtot, int nfBase)
{
    int gid = blockIdx.x * 256 + threadIdx.x;
    if (gid >= N * K) return;
    int n = gid / K, k = gid - n * K;
    int KS = K >> 5;
    float x = src[gid];
    bf16 hb = (bf16)x;                    // RNE
    bf16 lb = (bf16)(x - (float)hb);      // residual (exact in f32)
    int nf = nfBase + (n >> 4);
    int l  = (n & 15) | (((k & 31) >> 3) << 4);
    int ks = k >> 5;
    int e  = k & 7;
    int base = ((nf * KS + ks) << 9) + (l << 3) + e;
    int half = NFtot * KS * 512;
    dst[base] = hb;
    dst[half + base] = lb;
}

#define MFMA(a, b, c) __builtin_amdgcn_mfma_f32_16x16x32_bf16(a, b, c, 0, 0, 0)

// ---------------------------------------------------------------------------
// 2-term ODE streamer with static DEPTH-6 prefetch pipeline.
// hi*hi + lo*hi (W_lo never loaded). Fully unrolled -> all slot indices are
// compile-time; amdgpu_waves_per_eu(4,4) on the kernel unlocks the 128-VGPR
// tier so the ~12 in-flight 16B loads live in registers (no scratch).
// S layout: [half][ks][lane][8] bf16 (half stride 8192 elems).
// ---------------------------------------------------------------------------
template<int KS, int DEPTH>
__device__ __forceinline__ void mm_stream2p(const bf16* __restrict__ pk, int nf0, int lane,
                                            const bf16* __restrict__ S, f32x4* acc)
{
    const bf16* pb0 = pk + ((nf0 * KS) << 9) + (lane << 3);
    const bf16* pb1 = pk + (((nf0 + 1) * KS) << 9) + (lane << 3);
    bf16x8 b0[DEPTH], b1[DEPTH];
#pragma unroll
    for (int p = 0; p < DEPTH; ++p) {
        b0[p] = *(const bf16x8*)(pb0 + (p << 9));
        b1[p] = *(const bf16x8*)(pb1 + (p << 9));
    }
    f32x4 z = {0.f, 0.f, 0.f, 0.f};
    acc[0] = z; acc[1] = z;
#pragma unroll
    for (int ks = 0; ks < KS; ++ks) {
        const int sl = ks % DEPTH;
        bf16x8 ah = *(const bf16x8*)(S + ((ks << 6) + lane) * 8);
        bf16x8 al = *(const bf16x8*)(S + 8192 + ((ks << 6) + lane) * 8);
        acc[0] = MFMA(ah, b0[sl], acc[0]);
        acc[0] = MFMA(al, b0[sl], acc[0]);
        acc[1] = MFMA(ah, b1[sl], acc[1]);
        acc[1] = MFMA(al, b1[sl], acc[1]);
        if (ks + DEPTH < KS) {
            b0[sl] = *(const bf16x8*)(pb0 + ((ks + DEPTH) << 9));
            b1[sl] = *(const bf16x8*)(pb1 + ((ks + DEPTH) << 9));
        }
    }
}

// ---------------------------------------------------------------------------
// 3-term streamer (GRU gh phase): hi*hi + lo*hi + hi*lo. Proven round-2 code.
// NFR=6 already issues 12 loads per ks iteration (naturally deep).
// ---------------------------------------------------------------------------
template<int NFR, int KS, int NFtot, int STRIDE>
__device__ __forceinline__ void mm_stream(const bf16* __restrict__ pk, int nf0, int lane,
                                          const bf16* __restrict__ S, f32x4* acc)
{
    const int halfoff = NFtot * KS * 512;
#pragma unroll
    for (int i = 0; i < NFR; ++i) { f32x4 z = {0.f, 0.f, 0.f, 0.f}; acc[i] = z; }
#pragma unroll 2
    for (int ks = 0; ks < KS; ++ks) {
        bf16x8 ah = *(const bf16x8*)(S + ((ks << 6) + lane) * 8);
        bf16x8 al = *(const bf16x8*)(S + 8192 + ((ks << 6) + lane) * 8);
#pragma unroll
        for (int i = 0; i < NFR; ++i) {
            int nf = (i >> 1) * STRIDE + nf0 + (i & 1);
            const bf16* pb = pk + ((nf * KS + ks) << 9) + (lane << 3);
            bf16x8 bh = *(const bf16x8*)pb;
            bf16x8 bl = *(const bf16x8*)(pb + halfoff);
            acc[i] = MFMA(ah, bh, acc[i]);
            acc[i] = MFMA(al, bh, acc[i]);
            acc[i] = MFMA(ah, bl, acc[i]);
        }
    }
}

// A-frags from registers (K=128 x-input for the GRU gi GEMM), KS=4. 3-term.
template<int NFR, int NFtot, int STRIDE>
__device__ __forceinline__ void mm_x(const bf16* __restrict__ pk, int nf0, int lane,
                                     const bf16x8* xh, const bf16x8* xl, f32x4* acc)
{
    const int KS = 4;
    const int halfoff = NFtot * KS * 512;
#pragma unroll
    for (int i = 0; i < NFR; ++i) { f32x4 z = {0.f, 0.f, 0.f, 0.f}; acc[i] = z; }
#pragma unroll
    for (int ks = 0; ks < 4; ++ks)
#pragma unroll
        for (int i = 0; i < NFR; ++i) {
            int nf = (i >> 1) * STRIDE + nf0 + (i & 1);
            const bf16* pb = pk + ((nf * KS + ks) << 9) + (lane << 3);
            bf16x8 bh = *(const bf16x8*)pb;
            bf16x8 bl = *(const bf16x8*)(pb + halfoff);
            acc[i] = MFMA(xh[ks], bh, acc[i]);
            acc[i] = MFMA(xl[ks], bh, acc[i]);
            acc[i] = MFMA(xh[ks], bl, acc[i]);
        }
}

// scatter one f32 value (tile row r in [0,16), col c in [0,512)) into split LDS S
__device__ __forceinline__ void scat(bf16* __restrict__ Sp, int r, int c, float v)
{
    bf16 hb = (bf16)v;
    bf16 lb = (bf16)(v - (float)hb);
    int off = (((c >> 5) << 6) + (r | (((c & 31) >> 3) << 4))) * 8 + (c & 7);
    Sp[off] = hb;
    Sp[8192 + off] = lb;
}

// ---------------------------------------------------------------------------
// Persistent kernel: 64 blocks x 1024 threads (16 waves). Block owns 16 batch
// rows; h lives in per-thread REGISTERS (8 f32, ownership (rb+rg, c0+fi*16));
// split operands in 32 KB LDS. waves_per_eu(4,4) pins the 128-VGPR tier.
// ---------------------------------------------------------------------------
__global__ __attribute__((amdgpu_waves_per_eu(4, 4))) __launch_bounds__(1024)
void odegru_persist(const float* __restrict__ x, const float* __restrict__ t,
                    const float* __restrict__ bih, const float* __restrict__ bhh,
                    const float* __restrict__ b1,  const float* __restrict__ b2,
                    const float* __restrict__ bmu, const float* __restrict__ blv,
                    const bf16* __restrict__ pkW1, const bf16* __restrict__ pkW2,
                    const bf16* __restrict__ pkWhh, const bf16* __restrict__ pkWih,
                    const bf16* __restrict__ pkWout, float* __restrict__ out)
{
    __shared__ bf16 S[2 * 16 * 64 * 8];     // split operand buffer (32 KB)

    const int tid  = threadIdx.x;
    const int lane = tid & 63;
    const int w    = tid >> 6;              // wave 0..15
    const int li   = lane & 15, lh = lane >> 4;
    const int m0   = blockIdx.x << 4;       // batch-row base
    const int Tn = 128, In = 128;

    const int c0 = (w << 5) + li;           // wave's first output col + lane col
    const int rb = lh << 2;                 // C-frag row base

    float b1c[2], b2c[2], bihr[2], bihz[2], bihn[2], bhhr[2], bhhz[2], bhhn[2];
#pragma unroll
    for (int fi = 0; fi < 2; ++fi) {
        int c = c0 + (fi << 4);
        b1c[fi] = b1[c];  b2c[fi] = b2[c];
        bihr[fi] = bih[c]; bihz[fi] = bih[512 + c]; bihn[fi] = bih[1024 + c];
        bhhr[fi] = bhh[c]; bhhz[fi] = bhh[512 + c]; bhhn[fi] = bhh[1024 + c];
    }

    f32x4 acc[2];
    float ksum[2][4];
    float h8[2][4];                         // registered h (this thread's 8 cells)
    f32x4 giacc[6], ghacc[6];

    const int Ho = 8 * 16 * 512;            // pkWout halfelems

    for (int s = 0; s < 128; ++s) {
        const float dt = (s > 0) ? (t[s] - t[s - 1]) : 0.f;
        if (s > 0) {
            const float a01 = dt * 0.125f, a2 = dt * 0.25f, hk = dt * (1.f / 24.f);
#pragma unroll 1
            for (int sub = 0; sub < 4; ++sub) {
#pragma unroll 1
                for (int st = 0; st < 4; ++st) {
                    // phase A: tmp_pre = A @ W1^T   (A-split in S; 2-term, piped)
                    mm_stream2p<16, 6>(pkW1, w << 1, lane, S, acc);
                    __syncthreads();
                    // phase B: S = split(tanh(tmp_pre + b1))
#pragma unroll
                    for (int fi = 0; fi < 2; ++fi)
#pragma unroll
                        for (int rg = 0; rg < 4; ++rg)
                            scat(S, rb + rg, c0 + (fi << 4), tanhf(acc[fi][rg] + b1c[fi]));
                    __syncthreads();
                    // phase C: k = tmp @ W2^T  (2-term, piped)
                    mm_stream2p<16, 6>(pkW2, w << 1, lane, S, acc);
                    __syncthreads();
                    // phase D: RK4 combine; S = split(next A) or split(new h)
                    const float al = (st < 2) ? a01 : a2;
#pragma unroll
                    for (int fi = 0; fi < 2; ++fi)
#pragma unroll
                        for (int rg = 0; rg < 4; ++rg) {
                            float v = acc[fi][rg] + b2c[fi];
                            int c = c0 + (fi << 4);
                            if (st == 0) ksum[fi][rg] = v;
                            else if (st < 3) ksum[fi][rg] += 2.f * v;
                            float nv;
                            if (st < 3) {
                                nv = h8[fi][rg] + al * v;
                            } else {
                                nv = h8[fi][rg] + hk * (ksum[fi][rg] + v);
                                h8[fi][rg] = nv;
                            }
                            scat(S, rb + rg, c, nv);
                        }
                    __syncthreads();
                }
            }
        }
        // phase E: gi = x_s @ Wih^T  (x-frags in regs; no LDS use; 3-term)
        bf16x8 xh[4], xl[4];
        {
            const float* xp = x + ((long)(m0 + li) * Tn + s) * In + (lh << 3);
#pragma unroll
            for (int ks = 0; ks < 4; ++ks) {
                f32x4 v0 = *(const f32x4*)(xp + (ks << 5));
                f32x4 v1 = *(const f32x4*)(xp + (ks << 5) + 4);
                bf16x8 h8v, l8v;
#pragma unroll
                for (int j = 0; j < 4; ++j) {
                    bf16 hb = (bf16)v0[j]; h8v[j] = hb;     l8v[j] = (bf16)(v0[j] - (float)hb);
                    bf16 h2 = (bf16)v1[j]; h8v[4 + j] = h2; l8v[4 + j] = (bf16)(v1[j] - (float)h2);
                }
                xh[ks] = h8v; xl[ks] = l8v;
            }
        }
        mm_x<6, 96, 32>(pkWih, w << 1, lane, xh, xl, giacc);
        // phase F: gh = h @ Whh^T  (S still holds split(h); 3-term)
        if (s > 0) {
            mm_stream<6, 16, 96, 32>(pkWhh, w << 1, lane, S, ghacc);
        } else {
#pragma unroll
            for (int i = 0; i < 6; ++i) { f32x4 z = {0.f, 0.f, 0.f, 0.f}; ghacc[i] = z; }
        }
        __syncthreads();
        // phase G: GRU gates; h <- (1-z)*n + z*h; S = split(h_new)
#pragma unroll
        for (int fi = 0; fi < 2; ++fi)
#pragma unroll
            for (int rg = 0; rg < 4; ++rg) {
                int c = c0 + (fi << 4);
                float gr = giacc[fi][rg] + bihr[fi] + ghacc[fi][rg] + bhhr[fi];
                float gz = giacc[2 + fi][rg] + bihz[fi] + ghacc[2 + fi][rg] + bhhz[fi];
                float rr = 1.f / (1.f + __expf(-gr));
                float zz = 1.f / (1.f + __expf(-gz));
                float nn = tanhf(giacc[4 + fi][rg] + bihn[fi] + rr * (ghacc[4 + fi][rg] + bhhn[fi]));
                float hold = (s > 0) ? h8[fi][rg] : 0.f;
                float hn = (1.f - zz) * nn + zz * hold;
                h8[fi][rg] = hn;
                scat(S, rb + rg, c, hn);
            }
        __syncthreads();
    }
    // final: mu / logvar projections (S = split(h_T)); waves 0..7, 1 frag each
    if (w < 8) {
        f32x4 oacc[1];
        mm_stream<1, 16, 8, 0>(pkWout, w, lane, S, oacc);
        const float* bo = (w < 4) ? bmu : blv;
        int cl = ((w & 3) << 4) + li;
        float bv = bo[cl];
        float* ob = out + ((w < 4) ? 0 : 65536);
#pragma unroll
        for (int rg = 0; rg < 4; ++rg)
            ob[(long)(m0 + rb + rg) * 64 + cl] = oacc[0][rg] + bv;
    }
}

extern "C" void kernel_launch(void* const* d_in, const int* in_sizes, int n_in,
                              void* d_out, int out_size, void* d_ws, size_t ws_size,
                              hipStream_t stream)
{
    (void)in_sizes; (void)n_in; (void)out_size; (void)ws_size;
    const float* x   = (const float*)d_in[0];
    const float* t   = (const float*)d_in[1];
    const float* Wih = (const float*)d_in[2];
    const float* Whh = (const float*)d_in[3];
    const float* bih = (const float*)d_in[4];
    const float* bhh = (const float*)d_in[5];
    const float* W1  = (const float*)d_in[6];
    const float* b1  = (const float*)d_in[7];
    const float* W2  = (const float*)d_in[8];
    const float* b2  = (const float*)d_in[9];
    const float* Wmu = (const float*)d_in[10];
    const float* bmu = (const float*)d_in[11];
    const float* Wlv = (const float*)d_in[12];
    const float* blv = (const float*)d_in[13];
    float* out = (float*)d_out;

    bf16* pk1  = (bf16*)d_ws;             // 2*512*512   = 524288 elems (1 MB)
    bf16* pk2  = pk1 + 524288;            // 1 MB
    bf16* pkhh = pk2 + 524288;            // 2*1536*512  = 1572864 (3 MB)
    bf16* pkih = pkhh + 1572864;          // 2*1536*128  = 393216 (0.75 MB)
    bf16* pkout = pkih + 393216;          // 2*128*512   = 131072 (0.25 MB)

    pack_split<<<1024, 256, 0, stream>>>(W1,  pk1,  512, 512, 32, 0);
    pack_split<<<1024, 256, 0, stream>>>(W2,  pk2,  512, 512, 32, 0);
    pack_split<<<3072, 256, 0, stream>>>(Whh, pkhh, 1536, 512, 96, 0);
    pack_split<<<768,  256, 0, stream>>>(Wih, pkih, 1536, 128, 96, 0);
    pack_split<<<128,  256, 0, stream>>>(Wmu, pkout, 64, 512, 8, 0);
    pack_split<<<128,  256, 0, stream>>>(Wlv, pkout, 64, 512, 8, 4);

    odegru_persist<<<64, 1024, 0, stream>>>(x, t, bih, bhh, b1, b2, bmu, blv,
                                            pk1, pk2, pkhh, pkih, pkout, out);
}

// Round 8
// 53043.604 us; speedup vs baseline: 1.2505x; 1.2505x over previous
//
#include <hip/hip_runtime.h>
#include <stdint.h>

typedef __bf16 bf16;
typedef __bf16 bf16x8 __attribute__((ext_vector_type(8)));
typedef float f32x4 __attribute__((ext_vector_type(4)));

// ---------------------------------------------------------------------------
// Weight pre-pack: f32 [N,K] row-major -> split hi/lo bf16 in MFMA B-frag
// streaming layout: pk[half][nf][ks][lane][8],  lane = (n&15) | (((k&31)>>3)<<4),
// ks = k>>5, e = k&7.  One frag = 64 lanes x 16 B = 1 KB contiguous.
// ---------------------------------------------------------------------------
__global__ void pack_split(const float* __restrict__ src, bf16* __restrict__ dst,
                           int N, int K, int NFtot, int nfBase)
{
    int gid = blockIdx.x * 256 + threadIdx.x;
    if (gid >= N * K) return;
    int n = gid / K, k = gid - n * K;
    int KS = K >> 5;
    float x = src[gid];
    bf16 hb = (bf16)x;                    // RNE
    bf16 lb = (bf16)(x - (float)hb);      // residual (exact in f32)
    int nf = nfBase + (n >> 4);
    int l  = (n & 15) | (((k & 31) >> 3) << 4);
    int ks = k >> 5;
    int e  = k & 7;
    int base = ((nf * KS + ks) << 9) + (l << 3) + e;
    int half = NFtot * KS * 512;
    dst[base] = hb;
    dst[half + base] = lb;
}

#define MFMA(a, b, c) __builtin_amdgcn_mfma_f32_16x16x32_bf16(a, b, c, 0, 0, 0)

typedef __attribute__((address_space(3))) char* lds_ptr_t;

// stage the two hi-frags (nf0, nf0+1) of K-slice ks into the wave's ring slot
__device__ __forceinline__ void stage2(const bf16* __restrict__ pk, int nf0, int ks,
                                       int lane, lds_ptr_t dst)
{
    const bf16* g0 = pk + ((nf0 * 16 + ks) << 9) + (lane << 3);
    const bf16* g1 = pk + (((nf0 + 1) * 16 + ks) << 9) + (lane << 3);
    __builtin_amdgcn_global_load_lds(
        (const __attribute__((address_space(1))) unsigned int*)g0,
        (__attribute__((address_space(3))) unsigned int*)dst, 16, 0, 0);
    __builtin_amdgcn_global_load_lds(
        (const __attribute__((address_space(1))) unsigned int*)g1,
        (__attribute__((address_space(3))) unsigned int*)(dst + 1024), 16, 0, 0);
}

// ---------------------------------------------------------------------------
// ODE-phase GEMM via global_load_lds staging. 2-term split (hi*hi + lo*hi;
// W_lo never loaded). Per wave: private 3-slot x 2KB LDS ring; counted
// vmcnt (4/4/.../2/0); inline-asm ds_read_b128 for ring reads (C++ reads
// would force the compiler to drain vmcnt(0) -- alias analysis); lgkmcnt(0)
// + sched_barrier(0) before MFMA (rule #18); next stage issued after the
// slot's reads complete (no slot-reuse hazard).
// S layout: [half][ks][lane][8] bf16 (half stride 8192 elems).
// ---------------------------------------------------------------------------
#define ODE_STEP(KS_I, VMC)                                                     \
  {                                                                             \
    asm volatile("s_waitcnt vmcnt(" #VMC ")" ::: "memory");                     \
    f32x4 w0r, w1r;                                                             \
    unsigned ra = rb0 + ((KS_I) % 3) * 2048;                                    \
    asm volatile("ds_read_b128 %0, %2\n\t"                                      \
                 "ds_read_b128 %1, %2 offset:1024"                              \
                 : "=v"(w0r), "=v"(w1r) : "v"(ra) : "memory");                  \
    asm volatile("s_waitcnt lgkmcnt(0)" ::: "memory");                          \
    __builtin_amdgcn_sched_barrier(0);                                          \
    if ((KS_I) + 3 < 16) stage2(pk, nf0, (KS_I) + 3, lane, ringw + ((KS_I) % 3) * 2048); \
    bf16x8 w0 = __builtin_bit_cast(bf16x8, w0r);                                \
    bf16x8 w1 = __builtin_bit_cast(bf16x8, w1r);                                \
    bf16x8 ah = *(const bf16x8*)(S + (((KS_I) << 6) + lane) * 8);               \
    bf16x8 al = *(const bf16x8*)(S + 8192 + (((KS_I) << 6) + lane) * 8);        \
    acc[0] = MFMA(ah, w0, acc[0]);                                              \
    acc[0] = MFMA(al, w0, acc[0]);                                              \
    acc[1] = MFMA(ah, w1, acc[1]);                                              \
    acc[1] = MFMA(al, w1, acc[1]);                                              \
  }

__device__ __forceinline__ void mm_glds16(const bf16* __restrict__ pk, int nf0, int lane,
                                          const bf16* __restrict__ S, f32x4* acc,
                                          lds_ptr_t ringw)
{
    f32x4 z = {0.f, 0.f, 0.f, 0.f};
    acc[0] = z; acc[1] = z;
#pragma unroll
    for (int p = 0; p < 3; ++p) stage2(pk, nf0, p, lane, ringw + p * 2048);
    const unsigned rb0 = (unsigned)(uintptr_t)ringw + (unsigned)(lane << 4);
    ODE_STEP(0, 4)  ODE_STEP(1, 4)  ODE_STEP(2, 4)  ODE_STEP(3, 4)
    ODE_STEP(4, 4)  ODE_STEP(5, 4)  ODE_STEP(6, 4)  ODE_STEP(7, 4)
    ODE_STEP(8, 4)  ODE_STEP(9, 4)  ODE_STEP(10, 4) ODE_STEP(11, 4)
    ODE_STEP(12, 4) ODE_STEP(13, 4) ODE_STEP(14, 2) ODE_STEP(15, 0)
}

// ---------------------------------------------------------------------------
// 3-term streamer (GRU gh phase): hi*hi + lo*hi + hi*lo. Proven round-2 code.
// ---------------------------------------------------------------------------
template<int NFR, int KS, int NFtot, int STRIDE>
__device__ __forceinline__ void mm_stream(const bf16* __restrict__ pk, int nf0, int lane,
                                          const bf16* __restrict__ S, f32x4* acc)
{
    const int halfoff = NFtot * KS * 512;
#pragma unroll
    for (int i = 0; i < NFR; ++i) { f32x4 z = {0.f, 0.f, 0.f, 0.f}; acc[i] = z; }
#pragma unroll 2
    for (int ks = 0; ks < KS; ++ks) {
        bf16x8 ah = *(const bf16x8*)(S + ((ks << 6) + lane) * 8);
        bf16x8 al = *(const bf16x8*)(S + 8192 + ((ks << 6) + lane) * 8);
#pragma unroll
        for (int i = 0; i < NFR; ++i) {
            int nf = (i >> 1) * STRIDE + nf0 + (i & 1);
            const bf16* pb = pk + ((nf * KS + ks) << 9) + (lane << 3);
            bf16x8 bh = *(const bf16x8*)pb;
            bf16x8 bl = *(const bf16x8*)(pb + halfoff);
            acc[i] = MFMA(ah, bh, acc[i]);
            acc[i] = MFMA(al, bh, acc[i]);
            acc[i] = MFMA(ah, bl, acc[i]);
        }
    }
}

// A-frags from registers (K=128 x-input for the GRU gi GEMM), KS=4. 3-term.
template<int NFR, int NFtot, int STRIDE>
__device__ __forceinline__ void mm_x(const bf16* __restrict__ pk, int nf0, int lane,
                                     const bf16x8* xh, const bf16x8* xl, f32x4* acc)
{
    const int KS = 4;
    const int halfoff = NFtot * KS * 512;
#pragma unroll
    for (int i = 0; i < NFR; ++i) { f32x4 z = {0.f, 0.f, 0.f, 0.f}; acc[i] = z; }
#pragma unroll
    for (int ks = 0; ks < 4; ++ks)
#pragma unroll
        for (int i = 0; i < NFR; ++i) {
            int nf = (i >> 1) * STRIDE + nf0 + (i & 1);
            const bf16* pb = pk + ((nf * KS + ks) << 9) + (lane << 3);
            bf16x8 bh = *(const bf16x8*)pb;
            bf16x8 bl = *(const bf16x8*)(pb + halfoff);
            acc[i] = MFMA(xh[ks], bh, acc[i]);
            acc[i] = MFMA(xl[ks], bh, acc[i]);
            acc[i] = MFMA(xh[ks], bl, acc[i]);
        }
}

// scatter one f32 value (tile row r in [0,16), col c in [0,512)) into split LDS S
__device__ __forceinline__ void scat(bf16* __restrict__ Sp, int r, int c, float v)
{
    bf16 hb = (bf16)v;
    bf16 lb = (bf16)(v - (float)hb);
    int off = (((c >> 5) << 6) + (r | (((c & 31) >> 3) << 4))) * 8 + (c & 7);
    Sp[off] = hb;
    Sp[8192 + off] = lb;
}

// ---------------------------------------------------------------------------
// Persistent kernel: 64 blocks x 1024 threads (16 waves). Block owns 16 batch
// rows; h in per-thread registers; split operands in 32 KB static LDS; 96 KB
// dynamic LDS = per-wave gload_lds weight rings (3 slots x 2 KB x 16 waves).
// ---------------------------------------------------------------------------
__global__ __launch_bounds__(1024, 4)
void odegru_persist(const float* __restrict__ x, const float* __restrict__ t,
                    const float* __restrict__ bih, const float* __restrict__ bhh,
                    const float* __restrict__ b1,  const float* __restrict__ b2,
                    const float* __restrict__ bmu, const float* __restrict__ blv,
                    const bf16* __restrict__ pkW1, const bf16* __restrict__ pkW2,
                    const bf16* __restrict__ pkWhh, const bf16* __restrict__ pkWih,
                    const bf16* __restrict__ pkWout, float* __restrict__ out)
{
    __shared__ bf16 S[2 * 16 * 64 * 8];     // split operand buffer (32 KB)
    extern __shared__ char ringmem[];        // 96 KB: 16 waves x 3 x 2 KB

    const int tid  = threadIdx.x;
    const int lane = tid & 63;
    const int w    = tid >> 6;              // wave 0..15
    const int li   = lane & 15, lh = lane >> 4;
    const int m0   = blockIdx.x << 4;       // batch-row base
    const int Tn = 128, In = 128;

    lds_ptr_t ringw = (lds_ptr_t)ringmem + w * (3 * 2048);

    const int c0 = (w << 5) + li;           // wave's first output col + lane col
    const int rb = lh << 2;                 // C-frag row base

    float b1c[2], b2c[2], bihr[2], bihz[2], bihn[2], bhhr[2], bhhz[2], bhhn[2];
#pragma unroll
    for (int fi = 0; fi < 2; ++fi) {
        int c = c0 + (fi << 4);
        b1c[fi] = b1[c];  b2c[fi] = b2[c];
        bihr[fi] = bih[c]; bihz[fi] = bih[512 + c]; bihn[fi] = bih[1024 + c];
        bhhr[fi] = bhh[c]; bhhz[fi] = bhh[512 + c]; bhhn[fi] = bhh[1024 + c];
    }

    f32x4 acc[2];
    float ksum[2][4];
    float h8[2][4];                         // registered h (this thread's 8 cells)
    f32x4 giacc[6], ghacc[6];

    for (int s = 0; s < 128; ++s) {
        const float dt = (s > 0) ? (t[s] - t[s - 1]) : 0.f;
        if (s > 0) {
            const float a01 = dt * 0.125f, a2 = dt * 0.25f, hk = dt * (1.f / 24.f);
#pragma unroll 1
            for (int sub = 0; sub < 4; ++sub) {
#pragma unroll 1
                for (int st = 0; st < 4; ++st) {
                    // phase A: tmp_pre = A @ W1^T   (A-split in S; 2-term, staged)
                    mm_glds16(pkW1, w << 1, lane, S, acc, ringw);
                    __syncthreads();
                    // phase B: S = split(tanh(tmp_pre + b1))
#pragma unroll
                    for (int fi = 0; fi < 2; ++fi)
#pragma unroll
                        for (int rg = 0; rg < 4; ++rg)
                            scat(S, rb + rg, c0 + (fi << 4), tanhf(acc[fi][rg] + b1c[fi]));
                    __syncthreads();
                    // phase C: k = tmp @ W2^T  (2-term, staged)
                    mm_glds16(pkW2, w << 1, lane, S, acc, ringw);
                    __syncthreads();
                    // phase D: RK4 combine; S = split(next A) or split(new h)
                    const float al = (st < 2) ? a01 : a2;
#pragma unroll
                    for (int fi = 0; fi < 2; ++fi)
#pragma unroll
                        for (int rg = 0; rg < 4; ++rg) {
                            float v = acc[fi][rg] + b2c[fi];
                            int c = c0 + (fi << 4);
                            if (st == 0) ksum[fi][rg] = v;
                            else if (st < 3) ksum[fi][rg] += 2.f * v;
                            float nv;
                            if (st < 3) {
                                nv = h8[fi][rg] + al * v;
                            } else {
                                nv = h8[fi][rg] + hk * (ksum[fi][rg] + v);
                                h8[fi][rg] = nv;
                            }
                            scat(S, rb + rg, c, nv);
                        }
                    __syncthreads();
                }
            }
        }
        // phase E: gi = x_s @ Wih^T  (x-frags in regs; no LDS use; 3-term)
        bf16x8 xh[4], xl[4];
        {
            const float* xp = x + ((long)(m0 + li) * Tn + s) * In + (lh << 3);
#pragma unroll
            for (int ks = 0; ks < 4; ++ks) {
                f32x4 v0 = *(const f32x4*)(xp + (ks << 5));
                f32x4 v1 = *(const f32x4*)(xp + (ks << 5) + 4);
                bf16x8 h8v, l8v;
#pragma unroll
                for (int j = 0; j < 4; ++j) {
                    bf16 hb = (bf16)v0[j]; h8v[j] = hb;     l8v[j] = (bf16)(v0[j] - (float)hb);
                    bf16 h2 = (bf16)v1[j]; h8v[4 + j] = h2; l8v[4 + j] = (bf16)(v1[j] - (float)h2);
                }
                xh[ks] = h8v; xl[ks] = l8v;
            }
        }
        mm_x<6, 96, 32>(pkWih, w << 1, lane, xh, xl, giacc);
        // phase F: gh = h @ Whh^T  (S still holds split(h); 3-term)
        if (s > 0) {
            mm_stream<6, 16, 96, 32>(pkWhh, w << 1, lane, S, ghacc);
        } else {
#pragma unroll
            for (int i = 0; i < 6; ++i) { f32x4 z = {0.f, 0.f, 0.f, 0.f}; ghacc[i] = z; }
        }
        __syncthreads();
        // phase G: GRU gates; h <- (1-z)*n + z*h; S = split(h_new)
#pragma unroll
        for (int fi = 0; fi < 2; ++fi)
#pragma unroll
            for (int rg = 0; rg < 4; ++rg) {
                int c = c0 + (fi << 4);
                float gr = giacc[fi][rg] + bihr[fi] + ghacc[fi][rg] + bhhr[fi];
                float gz = giacc[2 + fi][rg] + bihz[fi] + ghacc[2 + fi][rg] + bhhz[fi];
                float rr = 1.f / (1.f + __expf(-gr));
                float zz = 1.f / (1.f + __expf(-gz));
                float nn = tanhf(giacc[4 + fi][rg] + bihn[fi] + rr * (ghacc[4 + fi][rg] + bhhn[fi]));
                float hold = (s > 0) ? h8[fi][rg] : 0.f;
                float hn = (1.f - zz) * nn + zz * hold;
                h8[fi][rg] = hn;
                scat(S, rb + rg, c, hn);
            }
        __syncthreads();
    }
    // final: mu / logvar projections (S = split(h_T)); waves 0..7, 1 frag each
    if (w < 8) {
        f32x4 oacc[1];
        mm_stream<1, 16, 8, 0>(pkWout, w, lane, S, oacc);
        const float* bo = (w < 4) ? bmu : blv;
        int cl = ((w & 3) << 4) + li;
        float bv = bo[cl];
        float* ob = out + ((w < 4) ? 0 : 65536);
#pragma unroll
        for (int rg = 0; rg < 4; ++rg)
            ob[(long)(m0 + rb + rg) * 64 + cl] = oacc[0][rg] + bv;
    }
}

extern "C" void kernel_launch(void* const* d_in, const int* in_sizes, int n_in,
                              void* d_out, int out_size, void* d_ws, size_t ws_size,
                              hipStream_t stream)
{
    (void)in_sizes; (void)n_in; (void)out_size; (void)ws_size;
    const float* x   = (const float*)d_in[0];
    const float* t   = (const float*)d_in[1];
    const float* Wih = (const float*)d_in[2];
    const float* Whh = (const float*)d_in[3];
    const float* bih = (const float*)d_in[4];
    const float* bhh = (const float*)d_in[5];
    const float* W1  = (const float*)d_in[6];
    const float* b1  = (const float*)d_in[7];
    const float* W2  = (const float*)d_in[8];
    const float* b2  = (const float*)d_in[9];
    const float* Wmu = (const float*)d_in[10];
    const float* bmu = (const float*)d_in[11];
    const float* Wlv = (const float*)d_in[12];
    const float* blv = (const float*)d_in[13];
    float* out = (float*)d_out;

    bf16* pk1  = (bf16*)d_ws;             // 2*512*512   = 524288 elems (1 MB)
    bf16* pk2  = pk1 + 524288;            // 1 MB
    bf16* pkhh = pk2 + 524288;            // 2*1536*512  = 1572864 (3 MB)
    bf16* pkih = pkhh + 1572864;          // 2*1536*128  = 393216 (0.75 MB)
    bf16* pkout = pkih + 393216;          // 2*128*512   = 131072 (0.25 MB)

    pack_split<<<1024, 256, 0, stream>>>(W1,  pk1,  512, 512, 32, 0);
    pack_split<<<1024, 256, 0, stream>>>(W2,  pk2,  512, 512, 32, 0);
    pack_split<<<3072, 256, 0, stream>>>(Whh, pkhh, 1536, 512, 96, 0);
    pack_split<<<768,  256, 0, stream>>>(Wih, pkih, 1536, 128, 96, 0);
    pack_split<<<128,  256, 0, stream>>>(Wmu, pkout, 64, 512, 8, 0);
    pack_split<<<128,  256, 0, stream>>>(Wlv, pkout, 64, 512, 8, 4);

    static int attr_set = 0;  // idempotent host-side attribute (not a stream op)
    if (!attr_set) {
        hipFuncSetAttribute((const void*)odegru_persist,
                            hipFuncAttributeMaxDynamicSharedMemorySize, 98304);
        attr_set = 1;
    }

    odegru_persist<<<64, 1024, 98304, stream>>>(x, t, bih, bhh, b1, b2, bmu, blv,
                                                pk1, pk2, pkhh, pkih, pkout, out);
}

// Round 9
// 26811.356 us; speedup vs baseline: 2.4739x; 1.9784x over previous
//
#include <hip/hip_runtime.h>
#include <stdint.h>

typedef __bf16 bf16;
typedef __bf16 bf16x8 __attribute__((ext_vector_type(8)));
typedef float f32x4 __attribute__((ext_vector_type(4)));

// ---------------------------------------------------------------------------
// Weight pre-pack: f32 [N,K] row-major -> split hi/lo bf16 in MFMA B-frag
// streaming layout: pk[half][nf][ks][lane][8],  lane = (n&15) | (((k&31)>>3)<<4),
// ks = k>>5, e = k&7.  One 16B load per (lane, nf, ks, half), fully coalesced.
// hi halves are contiguous (lo lives at +halfelems and is read only where the
// 3-term split is kept).
// ---------------------------------------------------------------------------
__global__ void pack_split(const float* __restrict__ src, bf16* __restrict__ dst,
                           int N, int K, int NFtot, int nfBase)
{
    int gid = blockIdx.x * 256 + threadIdx.x;
    if (gid >= N * K) return;
    int n = gid / K, k = gid - n * K;
    int KS = K >> 5;
    float x = src[gid];
    bf16 hb = (bf16)x;                    // RNE
    bf16 lb = (bf16)(x - (float)hb);      // residual (exact in f32)
    int nf = nfBase + (n >> 4);
    int l  = (n & 15) | (((k & 31) >> 3) << 4);
    int ks = k >> 5;
    int e  = k & 7;
    int base = ((nf * KS + ks) << 9) + (l << 3) + e;
    int half = NFtot * KS * 512;
    dst[base] = hb;
    dst[half + base] = lb;
}

#define MFMA(a, b, c) __builtin_amdgcn_mfma_f32_16x16x32_bf16(a, b, c, 0, 0, 0)

// ---------------------------------------------------------------------------
// 2-term streamer, contiguous frags (ODE phases): A_hi*W_hi + A_lo*W_hi.
// W_lo never loaded. Round-6 proven code.
// S layout: [half][ks][lane][8] bf16 (half stride 8192 elems).
// ---------------------------------------------------------------------------
template<int NFR, int KS>
__device__ __forceinline__ void mm_stream2(const bf16* __restrict__ pk, int nf0, int lane,
                                           const bf16* __restrict__ S, f32x4* acc)
{
#pragma unroll
    for (int i = 0; i < NFR; ++i) { f32x4 z = {0.f, 0.f, 0.f, 0.f}; acc[i] = z; }
#pragma unroll 2
    for (int ks = 0; ks < KS; ++ks) {
        bf16x8 ah = *(const bf16x8*)(S + ((ks << 6) + lane) * 8);
        bf16x8 al = *(const bf16x8*)(S + 8192 + ((ks << 6) + lane) * 8);
#pragma unroll
        for (int i = 0; i < NFR; ++i) {
            const bf16* pb = pk + (((nf0 + i) * KS + ks) << 9) + (lane << 3);
            bf16x8 bh = *(const bf16x8*)pb;
            acc[i] = MFMA(ah, bh, acc[i]);
            acc[i] = MFMA(al, bh, acc[i]);
        }
    }
}

// ---------------------------------------------------------------------------
// 2-term streamer, gate-strided frags (GRU gh phase): A_hi*W_hi + A_lo*W_hi.
// Whh_lo never loaded -> GRU read set shrinks; with ODE hi-only the full
// weight read set (~2.9 MB) fits the 4 MB per-XCD L2.
// ---------------------------------------------------------------------------
template<int NFR, int KS, int STRIDE>
__device__ __forceinline__ void mm_stream2g(const bf16* __restrict__ pk, int nf0, int lane,
                                            const bf16* __restrict__ S, f32x4* acc)
{
#pragma unroll
    for (int i = 0; i < NFR; ++i) { f32x4 z = {0.f, 0.f, 0.f, 0.f}; acc[i] = z; }
#pragma unroll 2
    for (int ks = 0; ks < KS; ++ks) {
        bf16x8 ah = *(const bf16x8*)(S + ((ks << 6) + lane) * 8);
        bf16x8 al = *(const bf16x8*)(S + 8192 + ((ks << 6) + lane) * 8);
#pragma unroll
        for (int i = 0; i < NFR; ++i) {
            int nf = (i >> 1) * STRIDE + nf0 + (i & 1);
            const bf16* pb = pk + ((nf * KS + ks) << 9) + (lane << 3);
            bf16x8 bh = *(const bf16x8*)pb;
            acc[i] = MFMA(ah, bh, acc[i]);
            acc[i] = MFMA(al, bh, acc[i]);
        }
    }
}

// 3-term streamer (kept ONLY for the final mu/logvar projection -- 0.25 MB once,
// output-critical): hi*hi + lo*hi + hi*lo.
template<int NFR, int KS, int NFtot, int STRIDE>
__device__ __forceinline__ void mm_stream(const bf16* __restrict__ pk, int nf0, int lane,
                                          const bf16* __restrict__ S, f32x4* acc)
{
    const int halfoff = NFtot * KS * 512;
#pragma unroll
    for (int i = 0; i < NFR; ++i) { f32x4 z = {0.f, 0.f, 0.f, 0.f}; acc[i] = z; }
#pragma unroll 2
    for (int ks = 0; ks < KS; ++ks) {
        bf16x8 ah = *(const bf16x8*)(S + ((ks << 6) + lane) * 8);
        bf16x8 al = *(const bf16x8*)(S + 8192 + ((ks << 6) + lane) * 8);
#pragma unroll
        for (int i = 0; i < NFR; ++i) {
            int nf = (i >> 1) * STRIDE + nf0 + (i & 1);
            const bf16* pb = pk + ((nf * KS + ks) << 9) + (lane << 3);
            bf16x8 bh = *(const bf16x8*)pb;
            bf16x8 bl = *(const bf16x8*)(pb + halfoff);
            acc[i] = MFMA(ah, bh, acc[i]);
            acc[i] = MFMA(al, bh, acc[i]);
            acc[i] = MFMA(ah, bl, acc[i]);
        }
    }
}

// A-frags from registers (K=128 x-input for the GRU gi GEMM), KS=4. 2-term:
// x_hi*W_hi + x_lo*W_hi (x_lo is free in regs; Wih_lo never loaded).
template<int NFR, int STRIDE>
__device__ __forceinline__ void mm_x2(const bf16* __restrict__ pk, int nf0, int lane,
                                      const bf16x8* xh, const bf16x8* xl, f32x4* acc)
{
    const int KS = 4;
#pragma unroll
    for (int i = 0; i < NFR; ++i) { f32x4 z = {0.f, 0.f, 0.f, 0.f}; acc[i] = z; }
#pragma unroll
    for (int ks = 0; ks < 4; ++ks)
#pragma unroll
        for (int i = 0; i < NFR; ++i) {
            int nf = (i >> 1) * STRIDE + nf0 + (i & 1);
            const bf16* pb = pk + ((nf * KS + ks) << 9) + (lane << 3);
            bf16x8 bh = *(const bf16x8*)pb;
            acc[i] = MFMA(xh[ks], bh, acc[i]);
            acc[i] = MFMA(xl[ks], bh, acc[i]);
        }
}

// scatter one f32 value (tile row r in [0,16), col c in [0,512)) into split LDS S
__device__ __forceinline__ void scat(bf16* __restrict__ Sp, int r, int c, float v)
{
    bf16 hb = (bf16)v;
    bf16 lb = (bf16)(v - (float)hb);
    int off = (((c >> 5) << 6) + (r | (((c & 31) >> 3) << 4))) * 8 + (c & 7);
    Sp[off] = hb;
    Sp[8192 + off] = lb;
}

// ---------------------------------------------------------------------------
// Persistent kernel: 64 blocks x 1024 threads (16 waves). Block owns 16 batch
// rows; h lives in LDS for the whole 128-step recurrence. Zero grid sync.
// (Round-6 structure verbatim; only the GRU streamers went 2-term.)
// ---------------------------------------------------------------------------
__global__ __launch_bounds__(1024, 4)
void odegru_persist(const float* __restrict__ x, const float* __restrict__ t,
                    const float* __restrict__ bih, const float* __restrict__ bhh,
                    const float* __restrict__ b1,  const float* __restrict__ b2,
                    const float* __restrict__ bmu, const float* __restrict__ blv,
                    const bf16* __restrict__ pkW1, const bf16* __restrict__ pkW2,
                    const bf16* __restrict__ pkWhh, const bf16* __restrict__ pkWih,
                    const bf16* __restrict__ pkWout, float* __restrict__ out)
{
    __shared__ float hbuf[16 * 512];        // h, f32 [row][col]      (32 KB)
    __shared__ bf16  S[2 * 16 * 64 * 8];    // split operand buffer   (32 KB)

    const int tid  = threadIdx.x;
    const int lane = tid & 63;
    const int w    = tid >> 6;              // wave 0..15
    const int li   = lane & 15, lh = lane >> 4;
    const int m0   = blockIdx.x << 4;       // batch-row base
    const int Tn = 128, In = 128;

    const int c0 = (w << 5) + li;           // wave's first output col + lane col
    const int rb = lh << 2;                 // C-frag row base

    float b1c[2], b2c[2], bihr[2], bihz[2], bihn[2], bhhr[2], bhhz[2], bhhn[2];
#pragma unroll
    for (int fi = 0; fi < 2; ++fi) {
        int c = c0 + (fi << 4);
        b1c[fi] = b1[c];  b2c[fi] = b2[c];
        bihr[fi] = bih[c]; bihz[fi] = bih[512 + c]; bihn[fi] = bih[1024 + c];
        bhhr[fi] = bhh[c]; bhhz[fi] = bhh[512 + c]; bhhn[fi] = bhh[1024 + c];
    }

    f32x4 acc[2];
    float ksum[2][4];
    f32x4 giacc[6], ghacc[6];

    for (int s = 0; s < 128; ++s) {
        const float dt = (s > 0) ? (t[s] - t[s - 1]) : 0.f;
        if (s > 0) {
            const float a01 = dt * 0.125f, a2 = dt * 0.25f, hk = dt * (1.f / 24.f);
#pragma unroll 1
            for (int sub = 0; sub < 4; ++sub) {
#pragma unroll 1
                for (int st = 0; st < 4; ++st) {
                    // phase A: tmp_pre = A @ W1^T   (A-split in S; 2-term)
                    mm_stream2<2, 16>(pkW1, w << 1, lane, S, acc);
                    __syncthreads();
                    // phase B: S = split(tanh(tmp_pre + b1))
#pragma unroll
                    for (int fi = 0; fi < 2; ++fi)
#pragma unroll
                        for (int rg = 0; rg < 4; ++rg)
                            scat(S, rb + rg, c0 + (fi << 4), tanhf(acc[fi][rg] + b1c[fi]));
                    __syncthreads();
                    // phase C: k = tmp @ W2^T  (2-term)
                    mm_stream2<2, 16>(pkW2, w << 1, lane, S, acc);
                    __syncthreads();
                    // phase D: RK4 combine; S = split(next A) or split(new h)
                    const float al = (st < 2) ? a01 : a2;
#pragma unroll
                    for (int fi = 0; fi < 2; ++fi)
#pragma unroll
                        for (int rg = 0; rg < 4; ++rg) {
                            float v = acc[fi][rg] + b2c[fi];
                            int c = c0 + (fi << 4);
                            int hoff = (rb + rg) * 512 + c;
                            if (st == 0) ksum[fi][rg] = v;
                            else if (st < 3) ksum[fi][rg] += 2.f * v;
                            float nv;
                            if (st < 3) {
                                nv = hbuf[hoff] + al * v;
                            } else {
                                nv = hbuf[hoff] + hk * (ksum[fi][rg] + v);
                                hbuf[hoff] = nv;
                            }
                            scat(S, rb + rg, c, nv);
                        }
                    __syncthreads();
                }
            }
        }
        // phase E: gi = x_s @ Wih^T  (x-frags in regs; 2-term, Wih_lo unread)
        bf16x8 xh[4], xl[4];
        {
            const float* xp = x + ((long)(m0 + li) * Tn + s) * In + (lh << 3);
#pragma unroll
            for (int ks = 0; ks < 4; ++ks) {
                f32x4 v0 = *(const f32x4*)(xp + (ks << 5));
                f32x4 v1 = *(const f32x4*)(xp + (ks << 5) + 4);
                bf16x8 h8v, l8v;
#pragma unroll
                for (int j = 0; j < 4; ++j) {
                    bf16 hb = (bf16)v0[j]; h8v[j] = hb;     l8v[j] = (bf16)(v0[j] - (float)hb);
                    bf16 h2 = (bf16)v1[j]; h8v[4 + j] = h2; l8v[4 + j] = (bf16)(v1[j] - (float)h2);
                }
                xh[ks] = h8v; xl[ks] = l8v;
            }
        }
        mm_x2<6, 32>(pkWih, w << 1, lane, xh, xl, giacc);
        // phase F: gh = h @ Whh^T  (S holds split(h); 2-term, Whh_lo unread)
        if (s > 0) {
            mm_stream2g<6, 16, 32>(pkWhh, w << 1, lane, S, ghacc);
        } else {
#pragma unroll
            for (int i = 0; i < 6; ++i) { f32x4 z = {0.f, 0.f, 0.f, 0.f}; ghacc[i] = z; }
        }
        __syncthreads();
        // phase G: GRU gates; h <- (1-z)*n + z*h; S = split(h_new)
#pragma unroll
        for (int fi = 0; fi < 2; ++fi)
#pragma unroll
            for (int rg = 0; rg < 4; ++rg) {
                int c = c0 + (fi << 4);
                int hoff = (rb + rg) * 512 + c;
                float gr = giacc[fi][rg] + bihr[fi] + ghacc[fi][rg] + bhhr[fi];
                float gz = giacc[2 + fi][rg] + bihz[fi] + ghacc[2 + fi][rg] + bhhz[fi];
                float rr = 1.f / (1.f + __expf(-gr));
                float zz = 1.f / (1.f + __expf(-gz));
                float nn = tanhf(giacc[4 + fi][rg] + bihn[fi] + rr * (ghacc[4 + fi][rg] + bhhn[fi]));
                float hold = (s > 0) ? hbuf[hoff] : 0.f;
                float hn = (1.f - zz) * nn + zz * hold;
                hbuf[hoff] = hn;
                scat(S, rb + rg, c, hn);
            }
        __syncthreads();
    }
    // final: mu / logvar projections (S = split(h_T)); waves 0..7, 3-term
    if (w < 8) {
        f32x4 oacc[1];
        mm_stream<1, 16, 8, 0>(pkWout, w, lane, S, oacc);
        const float* bo = (w < 4) ? bmu : blv;
        int cl = ((w & 3) << 4) + li;
        float bv = bo[cl];
        float* ob = out + ((w < 4) ? 0 : 65536);
#pragma unroll
        for (int rg = 0; rg < 4; ++rg)
            ob[(long)(m0 + rb + rg) * 64 + cl] = oacc[0][rg] + bv;
    }
}

extern "C" void kernel_launch(void* const* d_in, const int* in_sizes, int n_in,
                              void* d_out, int out_size, void* d_ws, size_t ws_size,
                              hipStream_t stream)
{
    (void)in_sizes; (void)n_in; (void)out_size; (void)ws_size;
    const float* x   = (const float*)d_in[0];
    const float* t   = (const float*)d_in[1];
    const float* Wih = (const float*)d_in[2];
    const float* Whh = (const float*)d_in[3];
    const float* bih = (const float*)d_in[4];
    const float* bhh = (const float*)d_in[5];
    const float* W1  = (const float*)d_in[6];
    const float* b1  = (const float*)d_in[7];
    const float* W2  = (const float*)d_in[8];
    const float* b2  = (const float*)d_in[9];
    const float* Wmu = (const float*)d_in[10];
    const float* bmu = (const float*)d_in[11];
    const float* Wlv = (const float*)d_in[12];
    const float* blv = (const float*)d_in[13];
    float* out = (float*)d_out;

    bf16* pk1  = (bf16*)d_ws;             // 2*512*512   = 524288 elems (1 MB)
    bf16* pk2  = pk1 + 524288;            // 1 MB
    bf16* pkhh = pk2 + 524288;            // 2*1536*512  = 1572864 (3 MB)
    bf16* pkih = pkhh + 1572864;          // 2*1536*128  = 393216 (0.75 MB)
    bf16* pkout = pkih + 393216;          // 2*128*512   = 131072 (0.25 MB)

    pack_split<<<1024, 256, 0, stream>>>(W1,  pk1,  512, 512, 32, 0);
    pack_split<<<1024, 256, 0, stream>>>(W2,  pk2,  512, 512, 32, 0);
    pack_split<<<3072, 256, 0, stream>>>(Whh, pkhh, 1536, 512, 96, 0);
    pack_split<<<768,  256, 0, stream>>>(Wih, pkih, 1536, 128, 96, 0);
    pack_split<<<128,  256, 0, stream>>>(Wmu, pkout, 64, 512, 8, 0);
    pack_split<<<128,  256, 0, stream>>>(Wlv, pkout, 64, 512, 8, 4);

    odegru_persist<<<64, 1024, 0, stream>>>(x, t, bih, bhh, b1, b2, bmu, blv,
                                            pk1, pk2, pkhh, pkih, pkout, out);
}